// Round 12
// baseline (6992.398 us; speedup 1.0000x reference)
//
#include <hip/hip_runtime.h>
#include <hip/hip_bf16.h>
#include <math.h>

#define N_ATOMS   50000
#define MAX_NB    6
#define HIDDEN    300
#define ATOM_FDIM 133
#define BOND_FDIM 14
#define PER_MOL   25
#define N_MOLS    2000
#define SCALE_INV (1.0f/17.320508075688772f)
#define LN_EPS    1e-5f

typedef unsigned short u16;

static __device__ __forceinline__ float bf2f(u16 u) {
    return __uint_as_float(((unsigned)u) << 16);
}
static __device__ __forceinline__ u16 f2bf(float f) {
    unsigned x = __float_as_uint(f);
    unsigned r = (x + 0x7fffu + ((x >> 16) & 1u)) >> 16;
    return (u16)r;
}

// ================================================================ weight prep
// Wqkb[300][316] = [Wq@Wk^T folded | zero-pad(2)], bf16
__global__ void k_prep_fold(const float* __restrict__ Wq, const float* __restrict__ Wk,
                            u16* __restrict__ Wqkb)
{
    int t = blockIdx.x * blockDim.x + threadIdx.x;
    if (t >= 300 * 316) return;
    int d = t / 316, j = t % 316;
    float s = 0.f;
    if (j < 314) {
        const float* wq = Wq + (size_t)d * 300;
        const float* wk = Wk + (size_t)j * 300;
        for (int h = 0; h < 300; ++h) s += wq[h] * wk[h];
    }
    Wqkb[t] = f2bf(s);
}

// cast Wv (90000), wih (270000), whh (270000) to bf16
__global__ void k_prep_cast(const float* __restrict__ Wv, const float* __restrict__ wih,
                            const float* __restrict__ whh,
                            u16* __restrict__ Wv_b, u16* __restrict__ wih_b, u16* __restrict__ whh_b)
{
    int t = blockIdx.x * blockDim.x + threadIdx.x;
    if (t < 90000)       Wv_b[t]            = f2bf(Wv[t]);
    else if (t < 360000) wih_b[t - 90000]   = f2bf(wih[t - 90000]);
    else if (t < 630000) whh_b[t - 360000]  = f2bf(whh[t - 360000]);
}

// ================================================================ msg0 = relu(f_atoms @ W_i)  -> bf16
__global__ __launch_bounds__(256)
void k_msg0(const float* __restrict__ A, const float* __restrict__ B, u16* __restrict__ C)
{
    __shared__ float As[16][64 + 1];
    __shared__ float Bs[16][64 + 1];
    const int tid = threadIdx.x;
    const int brow = blockIdx.y * 64, bcol = blockIdx.x * 64;
    const int tr = tid / 16, tc = tid % 16;
    float acc[4][4];
    #pragma unroll
    for (int i = 0; i < 4; ++i)
        #pragma unroll
        for (int j = 0; j < 4; ++j) acc[i][j] = 0.f;

    for (int k0 = 0; k0 < ATOM_FDIM; k0 += 16) {
        for (int i = tid; i < 64 * 16; i += 256) {
            int r = i / 16, c = i % 16;
            int gr = brow + r, gc = k0 + c;
            As[c][r] = (gr < N_ATOMS && gc < ATOM_FDIM) ? A[(size_t)gr * ATOM_FDIM + gc] : 0.f;
        }
        for (int i = tid; i < 16 * 64; i += 256) {
            int r = i / 64, c = i % 64;
            int gk = k0 + r, gc = bcol + c;
            Bs[r][c] = (gk < ATOM_FDIM && gc < HIDDEN) ? B[(size_t)gk * HIDDEN + gc] : 0.f;
        }
        __syncthreads();
        #pragma unroll
        for (int kk = 0; kk < 16; ++kk) {
            float a[4], b[4];
            #pragma unroll
            for (int i = 0; i < 4; ++i) a[i] = As[kk][tr * 4 + i];
            #pragma unroll
            for (int j = 0; j < 4; ++j) b[j] = Bs[kk][tc * 4 + j];
            #pragma unroll
            for (int i = 0; i < 4; ++i)
                #pragma unroll
                for (int j = 0; j < 4; ++j) acc[i][j] += a[i] * b[j];
        }
        __syncthreads();
    }
    #pragma unroll
    for (int i = 0; i < 4; ++i) {
        int gr = brow + tr * 4 + i;
        if (gr >= N_ATOMS) continue;
        #pragma unroll
        for (int j = 0; j < 4; ++j) {
            int gc = bcol + tc * 4 + j;
            if (gc >= HIDDEN) continue;
            C[(size_t)gr * HIDDEN + gc] = f2bf(fmaxf(acc[i][j], 0.f));
        }
    }
}

// ================================================================ bf16 GEMM: C = A[50000][300] @ B[300][ldb]
// cols < 300 -> C1 (stride 300); cols in [300,N) -> C2 (stride 14). BW = valid B width for loads.
__global__ __launch_bounds__(256)
void k_gemm_bf(const u16* __restrict__ A, const u16* __restrict__ B, int ldb, int BW, int N,
               u16* __restrict__ C1, u16* __restrict__ C2)
{
    __shared__ u16 As[64][16];      // [row][k] BK=12 (+pad)
    __shared__ u16 Bs[12][72];      // [k][col]
    const int tid = threadIdx.x;
    const int brow = blockIdx.y * 64, bcol = blockIdx.x * 64;
    const int tr = tid / 16, tc = tid % 16;
    float acc[4][4];
    #pragma unroll
    for (int i = 0; i < 4; ++i)
        #pragma unroll
        for (int j = 0; j < 4; ++j) acc[i][j] = 0.f;

    for (int k0 = 0; k0 < 300; k0 += 12) {
        if (tid < 192) {
            int r = tid / 3, c4 = (tid % 3) * 4;
            int gr = brow + r;
            ushort4 v = make_ushort4(0, 0, 0, 0);
            if (gr < N_ATOMS) v = *(const ushort4*)(A + (size_t)gr * 300 + k0 + c4);
            As[r][c4] = v.x; As[r][c4 + 1] = v.y; As[r][c4 + 2] = v.z; As[r][c4 + 3] = v.w;
        }
        if (tid < 192) {
            int r = tid / 16, c4 = (tid % 16) * 4;
            int gk = k0 + r, gc = bcol + c4;
            if (gc + 3 < BW) {
                ushort4 v = *(const ushort4*)(B + (size_t)gk * ldb + gc);
                Bs[r][c4] = v.x; Bs[r][c4 + 1] = v.y; Bs[r][c4 + 2] = v.z; Bs[r][c4 + 3] = v.w;
            } else {
                #pragma unroll
                for (int j = 0; j < 4; ++j)
                    Bs[r][c4 + j] = (gc + j < BW) ? B[(size_t)gk * ldb + gc + j] : (u16)0;
            }
        }
        __syncthreads();
        #pragma unroll
        for (int kk = 0; kk < 12; ++kk) {
            float a[4], b[4];
            #pragma unroll
            for (int i = 0; i < 4; ++i) a[i] = bf2f(As[tr * 4 + i][kk]);
            #pragma unroll
            for (int j = 0; j < 4; ++j) b[j] = bf2f(Bs[kk][tc * 4 + j]);
            #pragma unroll
            for (int i = 0; i < 4; ++i)
                #pragma unroll
                for (int j = 0; j < 4; ++j) acc[i][j] += a[i] * b[j];
        }
        __syncthreads();
    }
    #pragma unroll
    for (int i = 0; i < 4; ++i) {
        int gr = brow + tr * 4 + i;
        if (gr >= N_ATOMS) continue;
        #pragma unroll
        for (int j = 0; j < 4; ++j) {
            int gc = bcol + tc * 4 + j;
            if (gc >= N) continue;
            u16 v = f2bf(acc[i][j]);
            if (gc < 300) C1[(size_t)gr * 300 + gc] = v;
            else          C2[(size_t)gr * 14 + gc - 300] = v;
        }
    }
}

// ================================================================ scores + softmax -> wgt fp32 [50000][6]
__global__ __launch_bounds__(256)
void k_score(const u16* __restrict__ qk, const u16* __restrict__ qb,
             const u16* __restrict__ msg, const float* __restrict__ f_bonds,
             const int* __restrict__ a2a, const int* __restrict__ a2b,
             float* __restrict__ wgt)
{
    const int n = blockIdx.x * 4 + (threadIdx.x >> 6);
    if (n >= N_ATOMS) return;
    const int lane = threadIdx.x & 63;
    int idx[6], bidx[6];
    #pragma unroll
    for (int k = 0; k < 6; ++k) {
        idx[k]  = a2a[n * 6 + k];
        bidx[k] = a2b[n * 6 + k];
    }
    float p[6] = {0, 0, 0, 0, 0, 0};
    for (int h = lane; h < 300; h += 64) {
        float q = bf2f(qk[(size_t)n * 300 + h]);
        #pragma unroll
        for (int k = 0; k < 6; ++k) p[k] += q * bf2f(msg[(size_t)idx[k] * 300 + h]);
    }
    if (lane < 14) {
        float qv = bf2f(qb[(size_t)n * 14 + lane]);
        #pragma unroll
        for (int k = 0; k < 6; ++k) p[k] += qv * f_bonds[(size_t)bidx[k] * 14 + lane];
    }
    #pragma unroll
    for (int k = 0; k < 6; ++k)
        for (int o = 32; o > 0; o >>= 1) p[k] += __shfl_down(p[k], o);
    if (lane == 0) {
        float mx = -1e30f;
        #pragma unroll
        for (int k = 0; k < 6; ++k) { p[k] *= SCALE_INV; mx = fmaxf(mx, p[k]); }
        float tot = 0.f;
        #pragma unroll
        for (int k = 0; k < 6; ++k) { p[k] = expf(p[k] - mx); tot += p[k]; }
        float r = 1.f / tot;
        #pragma unroll
        for (int k = 0; k < 6; ++k) wgt[n * 6 + k] = p[k] * r;
    }
}

// ================================================================ attn + residual(recomputed inp) + relu + LN -> mw bf16
__global__ __launch_bounds__(256)
void k_attn_ln(const float* __restrict__ f_atoms, const float* __restrict__ W_i,
               const float* __restrict__ wgt, const u16* __restrict__ V,
               const int* __restrict__ a2a,
               const float* __restrict__ ln_g, const float* __restrict__ ln_b,
               u16* __restrict__ mw)
{
    const int n = blockIdx.x;
    const int tid = threadIdx.x;
    const int lane = tid & 63, wv = tid >> 6;
    __shared__ float fa[ATOM_FDIM];
    __shared__ float xs[HIDDEN];
    __shared__ float red[4][2];
    __shared__ float stat[2];
    __shared__ float wg[6];

    if (tid < ATOM_FDIM) fa[tid] = f_atoms[(size_t)n * ATOM_FDIM + tid];
    if (tid < 6) wg[tid] = wgt[n * 6 + tid];
    int idx[6];
    #pragma unroll
    for (int k = 0; k < 6; ++k) idx[k] = a2a[n * 6 + k];
    __syncthreads();

    float ls = 0.f, lq = 0.f;
    for (int h = tid; h < HIDDEN; h += 256) {
        float s = 0.f;
        #pragma unroll 7
        for (int k = 0; k < ATOM_FDIM; ++k) s += fa[k] * W_i[(size_t)k * HIDDEN + h];
        float a = 0.f;
        #pragma unroll
        for (int k = 0; k < 6; ++k) a += wg[k] * bf2f(V[(size_t)idx[k] * 300 + h]);
        float x = fmaxf(s + a, 0.f);
        xs[h] = x; ls += x; lq += x * x;
    }
    for (int o = 32; o > 0; o >>= 1) { ls += __shfl_down(ls, o); lq += __shfl_down(lq, o); }
    if (lane == 0) { red[wv][0] = ls; red[wv][1] = lq; }
    __syncthreads();
    if (tid == 0) {
        float s = red[0][0] + red[1][0] + red[2][0] + red[3][0];
        float q = red[0][1] + red[1][1] + red[2][1] + red[3][1];
        float mu = s / HIDDEN;
        float var = q / HIDDEN - mu * mu;
        stat[0] = mu; stat[1] = rsqrtf(var + LN_EPS);
    }
    __syncthreads();
    float mu = stat[0], rstd = stat[1];
    for (int h = tid; h < HIDDEN; h += 256)
        mw[(size_t)n * 300 + h] = f2bf((xs[h] - mu) * rstd * ln_g[h] + ln_b[h]);
}

// ================================================================ fused GRU GEMM (bf16 in/out, fp32 acc)
__global__ __launch_bounds__(256)
void k_gru(const u16* __restrict__ mwm, const u16* __restrict__ hold,
           const u16* __restrict__ wih, const u16* __restrict__ whh,
           const float* __restrict__ bih, const float* __restrict__ bhh,
           u16* __restrict__ hnew)
{
    __shared__ u16 A1s[64][16];
    __shared__ u16 A2s[64][16];
    __shared__ u16 Bs[6][12][72];
    const int tid = threadIdx.x;
    const int brow = blockIdx.y * 64, bcol = blockIdx.x * 64;
    const int tr = tid / 16, tc = tid % 16;
    float acc[6][4][4];
    #pragma unroll
    for (int g = 0; g < 6; ++g)
        #pragma unroll
        for (int i = 0; i < 4; ++i)
            #pragma unroll
            for (int j = 0; j < 4; ++j) acc[g][i][j] = 0.f;

    for (int k0 = 0; k0 < 300; k0 += 12) {
        if (tid < 192) {
            int r = tid / 3, c4 = (tid % 3) * 4;
            int gr = brow + r;
            ushort4 v1 = make_ushort4(0, 0, 0, 0), v2 = make_ushort4(0, 0, 0, 0);
            if (gr < N_ATOMS) {
                v1 = *(const ushort4*)(mwm  + (size_t)gr * 300 + k0 + c4);
                v2 = *(const ushort4*)(hold + (size_t)gr * 300 + k0 + c4);
            }
            A1s[r][c4] = v1.x; A1s[r][c4 + 1] = v1.y; A1s[r][c4 + 2] = v1.z; A1s[r][c4 + 3] = v1.w;
            A2s[r][c4] = v2.x; A2s[r][c4 + 1] = v2.y; A2s[r][c4 + 2] = v2.z; A2s[r][c4 + 3] = v2.w;
        }
        for (int c = tid; c < 1152; c += 256) {
            int g = c / 192, rem = c % 192;
            int r = rem / 16, c4 = (rem % 16) * 4;
            int gk = k0 + r, gc = bcol + c4;
            const u16* src = (g < 3) ? wih : whh;
            size_t base = (size_t)gk * 900 + (g % 3) * 300;
            if (gc + 3 < 300) {
                ushort4 v = *(const ushort4*)(src + base + gc);
                Bs[g][r][c4] = v.x; Bs[g][r][c4 + 1] = v.y; Bs[g][r][c4 + 2] = v.z; Bs[g][r][c4 + 3] = v.w;
            } else {
                #pragma unroll
                for (int j = 0; j < 4; ++j)
                    Bs[g][r][c4 + j] = (gc + j < 300) ? src[base + gc + j] : (u16)0;
            }
        }
        __syncthreads();
        #pragma unroll
        for (int kk = 0; kk < 12; ++kk) {
            float a1[4], a2[4];
            #pragma unroll
            for (int i = 0; i < 4; ++i) {
                a1[i] = bf2f(A1s[tr * 4 + i][kk]);
                a2[i] = bf2f(A2s[tr * 4 + i][kk]);
            }
            #pragma unroll
            for (int g = 0; g < 6; ++g) {
                float b[4];
                #pragma unroll
                for (int j = 0; j < 4; ++j) b[j] = bf2f(Bs[g][kk][tc * 4 + j]);
                const float* a = (g < 3) ? a1 : a2;
                #pragma unroll
                for (int i = 0; i < 4; ++i)
                    #pragma unroll
                    for (int j = 0; j < 4; ++j) acc[g][i][j] += a[i] * b[j];
            }
        }
        __syncthreads();
    }
    #pragma unroll
    for (int i = 0; i < 4; ++i) {
        int gr = brow + tr * 4 + i;
        if (gr >= N_ATOMS) continue;
        #pragma unroll
        for (int j = 0; j < 4; ++j) {
            int gc = bcol + tc * 4 + j;
            if (gc >= 300) continue;
            float g_r = acc[0][i][j] + bih[gc]       + acc[3][i][j] + bhh[gc];
            float g_z = acc[1][i][j] + bih[300 + gc] + acc[4][i][j] + bhh[300 + gc];
            float r = 1.f / (1.f + expf(-g_r));
            float z = 1.f / (1.f + expf(-g_z));
            float nn = tanhf(acc[2][i][j] + bih[600 + gc] + r * (acc[5][i][j] + bhh[600 + gc]));
            size_t o = (size_t)gr * 300 + gc;
            float h_old = bf2f(hold[o]);
            hnew[o] = f2bf((1.f - z) * nn + z * h_old);
        }
    }
}

// ================================================================ amsg = sum_k msg[a2a] -> bf16 (into dead msg buffer)
__global__ void k_amsg(const u16* __restrict__ msg, const int* __restrict__ a2a, u16* __restrict__ amsg)
{
    int i = blockIdx.x * blockDim.x + threadIdx.x;
    if (i >= N_ATOMS * HIDDEN) return;
    int n = i / HIDDEN, h = i % HIDDEN;
    const int* nb = a2a + n * 6;
    float s = 0.f;
    #pragma unroll
    for (int k = 0; k < 6; ++k) s += bf2f(msg[(size_t)nb[k] * 300 + h]);
    amsg[i] = f2bf(s);
}

// ================================================================ atom_hiddens = relu([f_atoms|amsg] @ W_o + b_o) -> bf16
__global__ __launch_bounds__(256)
void k_final(const float* __restrict__ f_atoms, const u16* __restrict__ amsg,
             const float* __restrict__ W_o, const float* __restrict__ b_o,
             u16* __restrict__ C)
{
    __shared__ float As[16][64 + 1];
    __shared__ float Bs[16][64 + 1];
    const int tid = threadIdx.x;
    const int brow = blockIdx.y * 64, bcol = blockIdx.x * 64;
    const int tr = tid / 16, tc = tid % 16;
    float acc[4][4];
    #pragma unroll
    for (int i = 0; i < 4; ++i)
        #pragma unroll
        for (int j = 0; j < 4; ++j) acc[i][j] = 0.f;

    for (int k0 = 0; k0 < 433; k0 += 16) {
        for (int i = tid; i < 64 * 16; i += 256) {
            int r = i / 16, c = i % 16;
            int gr = brow + r, gc = k0 + c;
            float v = 0.f;
            if (gr < N_ATOMS && gc < 433)
                v = (gc < ATOM_FDIM) ? f_atoms[(size_t)gr * ATOM_FDIM + gc]
                                     : bf2f(amsg[(size_t)gr * 300 + gc - ATOM_FDIM]);
            As[c][r] = v;
        }
        for (int i = tid; i < 16 * 64; i += 256) {
            int r = i / 64, c = i % 64;
            int gk = k0 + r, gc = bcol + c;
            Bs[r][c] = (gk < 433 && gc < HIDDEN) ? W_o[(size_t)gk * HIDDEN + gc] : 0.f;
        }
        __syncthreads();
        #pragma unroll
        for (int kk = 0; kk < 16; ++kk) {
            float a[4], b[4];
            #pragma unroll
            for (int i = 0; i < 4; ++i) a[i] = As[kk][tr * 4 + i];
            #pragma unroll
            for (int j = 0; j < 4; ++j) b[j] = Bs[kk][tc * 4 + j];
            #pragma unroll
            for (int i = 0; i < 4; ++i)
                #pragma unroll
                for (int j = 0; j < 4; ++j) acc[i][j] += a[i] * b[j];
        }
        __syncthreads();
    }
    #pragma unroll
    for (int i = 0; i < 4; ++i) {
        int gr = brow + tr * 4 + i;
        if (gr >= N_ATOMS) continue;
        #pragma unroll
        for (int j = 0; j < 4; ++j) {
            int gc = bcol + tc * 4 + j;
            if (gc >= HIDDEN) continue;
            C[(size_t)gr * HIDDEN + gc] = f2bf(fmaxf(acc[i][j] + b_o[gc], 0.f));
        }
    }
}

// ================================================================ per-molecule mean
__global__ void k_mol(const u16* __restrict__ ah, float* __restrict__ out)
{
    int i = blockIdx.x * blockDim.x + threadIdx.x;
    if (i >= N_MOLS * HIDDEN) return;
    int m = i / HIDDEN, h = i % HIDDEN;
    const u16* base = ah + (size_t)m * PER_MOL * HIDDEN + h;
    float s = 0.f;
    #pragma unroll
    for (int a = 0; a < PER_MOL; ++a) s += bf2f(base[(size_t)a * HIDDEN]);
    out[i] = s * (1.f / (float)PER_MOL);
}

// ================================================================ launch
extern "C" void kernel_launch(void* const* d_in, const int* in_sizes, int n_in,
                              void* d_out, int out_size, void* d_ws, size_t ws_size,
                              hipStream_t stream)
{
    const float* f_atoms = (const float*)d_in[0];
    const float* f_bonds = (const float*)d_in[1];
    const int*   a2a     = (const int*)d_in[2];
    const int*   a2b     = (const int*)d_in[3];
    const float* W_i     = (const float*)d_in[4];
    const float* Wk      = (const float*)d_in[5];
    const float* Wq      = (const float*)d_in[6];
    const float* Wv      = (const float*)d_in[7];
    const float* ln_g    = (const float*)d_in[8];
    const float* ln_b    = (const float*)d_in[9];
    const float* gru_wih = (const float*)d_in[10];
    const float* gru_whh = (const float*)d_in[11];
    const float* gru_bih = (const float*)d_in[12];
    const float* gru_bhh = (const float*)d_in[13];
    const float* W_o     = (const float*)d_in[14];
    const float* b_o     = (const float*)d_in[15];
    float* out = (float*)d_out;

    // byte layout (all bf16 u16 unless noted):
    //   msgA 30,000,000 | msgB 30,000,000 | tv 30,000,000 | mw 30,000,000
    //   qb 1,400,000 | wgt(f32) 1,200,000 | Wqkb 189,600 | Wv 180,000 | wih 540,000 | whh 540,000
    // total = 124,049,600 B
    const size_t NEED = 124049600ull;
    if (ws_size < NEED) return;

    char* p = (char*)d_ws;
    u16*   msgA = (u16*)(p);
    u16*   msgB = (u16*)(p + 30000000);
    u16*   tv   = (u16*)(p + 60000000);
    u16*   mw   = (u16*)(p + 90000000);
    u16*   qb   = (u16*)(p + 120000000);
    float* wgt  = (float*)(p + 121400000);
    u16*   Wqkb = (u16*)(p + 122600000);
    u16*   Wv_b = (u16*)(p + 122789600);
    u16*   wih_b= (u16*)(p + 122969600);
    u16*   whh_b= (u16*)(p + 123509600);

    // weight prep
    k_prep_fold<<<(300 * 316 + 255) / 256, 256, 0, stream>>>(Wq, Wk, Wqkb);
    k_prep_cast<<<(630000 + 255) / 256, 256, 0, stream>>>(Wv, gru_wih, gru_whh, Wv_b, wih_b, whh_b);

    // msg0
    {
        dim3 g((HIDDEN + 63) / 64, (N_ATOMS + 63) / 64);
        k_msg0<<<g, 256, 0, stream>>>(f_atoms, W_i, msgA);
    }

    u16* msrc = msgA;
    u16* mdst = msgB;
    for (int it = 0; it < 2; ++it) {
        // qk|qb = msg @ Wqkb   (N=314, ldb=316 zero-padded)
        {
            dim3 g((314 + 63) / 64, (N_ATOMS + 63) / 64);
            k_gemm_bf<<<g, 256, 0, stream>>>(msrc, Wqkb, 316, 316, 314, tv, qb);
        }
        // scores + softmax
        k_score<<<(N_ATOMS + 3) / 4, 256, 0, stream>>>(tv, qb, msrc, f_bonds, a2a, a2b, wgt);
        // V = msg @ Wv (overwrites tv)
        {
            dim3 g((300 + 63) / 64, (N_ATOMS + 63) / 64);
            k_gemm_bf<<<g, 256, 0, stream>>>(msrc, Wv_b, 300, 300, 300, tv, qb);
        }
        // attn + recomputed inp + relu + LN -> mw
        k_attn_ln<<<N_ATOMS, 256, 0, stream>>>(f_atoms, W_i, wgt, tv, a2a, ln_g, ln_b, mw);
        // GRU -> mdst
        {
            dim3 g((300 + 63) / 64, (N_ATOMS + 63) / 64);
            k_gru<<<g, 256, 0, stream>>>(mw, msrc, wih_b, whh_b, gru_bih, gru_bhh, mdst);
        }
        u16* t = msrc; msrc = mdst; mdst = t;
    }
    // msrc = final message (msgA). amsg -> msgB (dead)
    k_amsg<<<(N_ATOMS * HIDDEN + 255) / 256, 256, 0, stream>>>(msrc, a2a, mdst);
    // atom_hiddens -> tv (dead)
    {
        dim3 g((HIDDEN + 63) / 64, (N_ATOMS + 63) / 64);
        k_final<<<g, 256, 0, stream>>>(f_atoms, mdst, W_o, b_o, tv);
    }
    // molecule mean
    k_mol<<<(N_MOLS * HIDDEN + 255) / 256, 256, 0, stream>>>(tv, out);
}